// Round 2
// baseline (199.773 us; speedup 1.0000x reference)
//
#include <hip/hip_runtime.h>
#include <hip/hip_bf16.h>
#include <math.h>

#define HW 3136
#define NC 192
#define NHEADS 6
#define IMG 56
#define NATT 486
#define YSTR 768           // Y row: [0,192)=v, [192,768)=att head*96 + k*10 + l
#define ATT_SCALE 0.17677669529663687f  // 32^-0.5

typedef __attribute__((ext_vector_type(8))) short short8;
typedef __attribute__((ext_vector_type(8))) unsigned short ushort8;
typedef __attribute__((ext_vector_type(4))) float float4v;

__device__ __forceinline__ float bf2f(unsigned short u) {
    unsigned int x = ((unsigned int)u) << 16;
    return __builtin_bit_cast(float, x);
}
__device__ __forceinline__ unsigned short f2bf(float f) {
    __hip_bfloat16 h = __float2bfloat16(f);
    return __builtin_bit_cast(unsigned short, h);
}
__device__ __forceinline__ void gload_lds16(const void* g, void* l) {
    __builtin_amdgcn_global_load_lds((const __attribute__((address_space(1))) void*)g,
                                     (__attribute__((address_space(3))) void*)l, 16, 0, 0);
}

// x [16][192][3136] fp32 -> xt [50176][192] bf16 (channels-last). grid (784,3), block 256.
__global__ __launch_bounds__(256) void transpose_x(const float* __restrict__ x,
                                                   unsigned short* __restrict__ xt)
{
    __shared__ float tile[64][65];
    int bx = blockIdx.x;
    int n = (bx * 64) / HW;
    int hw0 = (bx * 64) % HW;
    int c0 = blockIdx.y * 64;
    int tl = threadIdx.x & 63, tg = threadIdx.x >> 6;
    const float* xn = x + (size_t)n * NC * HW;
#pragma unroll
    for (int i = 0; i < 16; ++i)
        tile[tg * 16 + i][tl] = xn[(size_t)(c0 + tg * 16 + i) * HW + hw0 + tl];
    __syncthreads();
    unsigned short* xp = xt + ((size_t)n * HW + hw0) * NC + c0;
#pragma unroll
    for (int i = 0; i < 16; ++i) {
        int hwr = tg * 16 + i;
        xp[(size_t)hwr * NC + tl] = f2bf(tile[tl][hwr]);
    }
}

// Weight prep: Wall[768][192] = [Wv^T ; Wa^T permuted, stride 10], ball[768],
// Wpt[192][192] = Wp^T. grid 576, block 256.
__global__ __launch_bounds__(256) void prep_weights(
    const float* __restrict__ Wv, const float* __restrict__ Wa, const float* __restrict__ Wp,
    const float* __restrict__ ba,
    unsigned short* __restrict__ Wall, unsigned short* __restrict__ Wpt,
    float* __restrict__ ball)
{
    int idx = blockIdx.x * 256 + threadIdx.x;
    if (idx < 36864) {
        int d = idx / 192, k = idx - d * 192;
        Wpt[idx] = f2bf(Wp[(size_t)k * NC + d]);
    }
    if (idx < 147456) {                       // 768*192
        int d = idx / 192, k = idx - d * 192;
        unsigned short val;
        float bv = 0.f;
        if (d < 192) {
            val = f2bf(Wv[(size_t)k * NC + d]);
        } else {
            int dp = d - 192;                 // 0..575
            int head = dp / 96, rr = dp - head * 96;
            int k9 = rr / 10, l = rr - k9 * 10;
            bool valid = (k9 < 9) && (l < 9);
            int src = head * 81 + k9 * 9 + l;
            val = valid ? f2bf(Wa[(size_t)k * NATT + src]) : (unsigned short)0;
            bv = valid ? ba[src] : 0.f;
        }
        Wall[idx] = val;
        if (k == 0) ball[d] = bv;
    }
}

// Y[row][col] = sum_k xt[row][k]*Wall[col][k] + ball[col], bf16 out.
// 128x128 tile, 4 waves of 64x64 (4x4 acc), K=192 in 6 dbuf steps, glds16 staging.
// grid (6, 392).
__global__ __launch_bounds__(256) void gemm_big(
    const unsigned short* __restrict__ A, const unsigned short* __restrict__ W,
    const float* __restrict__ ball, unsigned short* __restrict__ Y)
{
    __shared__ __align__(16) unsigned short As[2][4096];
    __shared__ __align__(16) unsigned short Bs[2][4096];
    int t = threadIdx.x, lane = t & 63, wave = t >> 6;
    int col0 = blockIdx.x * 128, row0 = blockIdx.y * 128;
    int fr = lane & 15, fq = lane >> 4;
    int wm = (wave >> 1) * 64, wn = (wave & 1) * 64;
    int srow = lane >> 2;          // 0..15
    int soff = (lane & 3) * 16;    // byte offset within a 64-B k-row chunk
    const char* Ab = (const char*)A;
    const char* Wb = (const char*)W;

    float4v acc[4][4] = {};

#define STAGE_BIG(buf, k0)                                                        \
    {                                                                             \
        _Pragma("unroll")                                                         \
        for (int i = 0; i < 2; ++i) {                                             \
            int j = wave * 2 + i;                                                 \
            gload_lds16(Ab + (size_t)(row0 + j * 16 + srow) * 384 + (k0)*2 + soff,\
                        (char*)As[buf] + j * 1024);                               \
            gload_lds16(Wb + (size_t)(col0 + j * 16 + srow) * 384 + (k0)*2 + soff,\
                        (char*)Bs[buf] + j * 1024);                               \
        }                                                                         \
    }

    STAGE_BIG(0, 0);
    for (int s = 0; s < 6; ++s) {
        if (s < 5) STAGE_BIG((s + 1) & 1, (s + 1) * 32);
        __syncthreads();
        int buf = s & 1;
        short8 af[4], bf[4];
#pragma unroll
        for (int mi = 0; mi < 4; ++mi)
            af[mi] = *(const short8*)((const char*)As[buf] + (wm + mi * 16 + fr) * 64 + fq * 16);
#pragma unroll
        for (int ni = 0; ni < 4; ++ni)
            bf[ni] = *(const short8*)((const char*)Bs[buf] + (wn + ni * 16 + fr) * 64 + fq * 16);
#pragma unroll
        for (int mi = 0; mi < 4; ++mi)
#pragma unroll
            for (int ni = 0; ni < 4; ++ni)
                acc[mi][ni] = __builtin_amdgcn_mfma_f32_16x16x32_bf16(
                    af[mi], bf[ni], acc[mi][ni], 0, 0, 0);
        __syncthreads();
    }

#pragma unroll
    for (int ni = 0; ni < 4; ++ni) {
        int col = col0 + wn + ni * 16 + fr;
        float b = ball[col];
#pragma unroll
        for (int mi = 0; mi < 4; ++mi) {
            int row = row0 + wm + mi * 16 + fq * 4;
#pragma unroll
            for (int r = 0; r < 4; ++r)
                Y[(size_t)(row + r) * YSTR + col] = f2bf(acc[mi][ni][r] + b);
        }
    }
#undef STAGE_BIG
}

// out[img][m][phw] = sum_k Wpt[m][k]*fold[n][k] + bias[m]; 64(m) x 256(n) tile.
// grid (196, 3), block 256, 4 waves each 64x64.
__global__ __launch_bounds__(256) void gemm_small(
    const unsigned short* __restrict__ A,   // Wpt [192][192]
    const unsigned short* __restrict__ B,   // fold [50176][192]
    const float* __restrict__ bias, float* __restrict__ out)
{
    __shared__ __align__(16) unsigned short As[2][2048];
    __shared__ __align__(16) unsigned short Bs[2][8192];
    int t = threadIdx.x, lane = t & 63, wave = t >> 6;
    int n0 = blockIdx.x * 256, m0 = blockIdx.y * 64;
    int fr = lane & 15, fq = lane >> 4;
    int srow = lane >> 2, soff = (lane & 3) * 16;
    const char* Ab = (const char*)A;
    const char* Bb = (const char*)B;

    float4v acc[4][4] = {};

#define STAGE_SMALL(buf, k0)                                                      \
    {                                                                             \
        gload_lds16(Ab + (size_t)(m0 + wave * 16 + srow) * 384 + (k0)*2 + soff,   \
                    (char*)As[buf] + wave * 1024);                                \
        _Pragma("unroll")                                                         \
        for (int i = 0; i < 4; ++i) {                                             \
            int j = wave * 4 + i;                                                 \
            gload_lds16(Bb + (size_t)(n0 + j * 16 + srow) * 384 + (k0)*2 + soff,  \
                        (char*)Bs[buf] + j * 1024);                               \
        }                                                                         \
    }

    STAGE_SMALL(0, 0);
    for (int s = 0; s < 6; ++s) {
        if (s < 5) STAGE_SMALL((s + 1) & 1, (s + 1) * 32);
        __syncthreads();
        int buf = s & 1;
        short8 af[4], bf[4];
#pragma unroll
        for (int mi = 0; mi < 4; ++mi)
            af[mi] = *(const short8*)((const char*)As[buf] + (mi * 16 + fr) * 64 + fq * 16);
#pragma unroll
        for (int ni = 0; ni < 4; ++ni)
            bf[ni] = *(const short8*)((const char*)Bs[buf] + (wave * 64 + ni * 16 + fr) * 64 + fq * 16);
#pragma unroll
        for (int mi = 0; mi < 4; ++mi)
#pragma unroll
            for (int ni = 0; ni < 4; ++ni)
                acc[mi][ni] = __builtin_amdgcn_mfma_f32_16x16x32_bf16(
                    af[mi], bf[ni], acc[mi][ni], 0, 0, 0);
        __syncthreads();
    }

#pragma unroll
    for (int ni = 0; ni < 4; ++ni) {
        int n = n0 + wave * 64 + ni * 16 + fr;
        int img = n / HW, phw = n - img * HW;
        float* op = out + (size_t)img * (NC * HW) + phw;
#pragma unroll
        for (int mi = 0; mi < 4; ++mi) {
            int m = m0 + mi * 16 + fq * 4;
#pragma unroll
            for (int r = 0; r < 4; ++r)
                op[(size_t)(m + r) * HW] = acc[mi][ni][r] + bias[m + r];
        }
    }
#undef STAGE_SMALL
}

// Fused softmax + weight-combine + aggregation, v6: conflict-free LDS banks.
// Block = one head x (8x28) image tile (224 positions, 256 threads).
// LDS halo layout: 4 q-planes (16-B channel quarters), plane stride 433 chunks
// (6928 B), row stride 36 chunks (576 B; 36 mod 8 = 4).
//  - WRITES are plane-major (q = u/384): each 16-lane phase writes 16
//    consecutive chunks -> exactly 2 rows per bank-quad (minimum).
//  - READS at (ph+dy)*36 + (pw+dx), uniform q: every 16-lane phase of the
//    ph=t/28,pw=t%28 map hits each bank-quad exactly 2x (stride 4 mod 8
//    rebalances the 28-wide row wrap). dy/dx fold into ds_read immediates.
__global__ __launch_bounds__(256, 4) void fused_att_agg(
    const unsigned short* __restrict__ Y, unsigned short* __restrict__ fold)
{
    __shared__ __align__(16) char vt[27712];    // 4 planes x 433 chunks x 16 B
    int t = threadIdx.x;
    int bid = blockIdx.x;
    int head = bid % NHEADS; int tmp = bid / NHEADS;
    int tcol = tmp & 1; tmp >>= 1;
    int trow = tmp % 7; int img = tmp / 7;
    int h0 = trow * 8, w0 = tcol * 28;

    // ---- issue v-halo loads into registers (clamped addr + zero mask) ----
    // plane-major item index: u = q*384 + vrow*32 + vcol
    const unsigned short* Yv = Y + head * 32;
    ushort8 stg[6];
#pragma unroll
    for (int i = 0; i < 6; ++i) {
        int u = i * 256 + t;                 // 0..1535
        int q = u / 384;                     // ch quarter, uniform per wave
        int idx = u - q * 384;               // 0..383
        int vrow = idx >> 5, vcol = idx & 31;
        int hh = h0 - 2 + vrow, ww = w0 - 2 + vcol;
        bool ok = (hh >= 0) & (hh < IMG) & (ww >= 0) & (ww < IMG);
        int hc = min(max(hh, 0), IMG - 1);
        int wcl = min(max(ww, 0), IMG - 1);
        ushort8 val = *(const ushort8*)(Yv + (size_t)(img * HW + hc * IMG + wcl) * YSTR + q * 8);
        if (!ok) val = (ushort8){};
        stg[i] = val;
    }

    // ---- softmax -> 5x5 stencil weights, fully in registers ----
    int ph = t / 28, pw = t - (t / 28) * 28;
    int h = h0 + ph, w = w0 + pw;
    float wc[25];
#pragma unroll
    for (int d = 0; d < 25; ++d) wc[d] = 0.f;
    if (t < 224) {
        const unsigned short* Yatt = Y + 192 + head * 96;
#pragma unroll
        for (int k = 0; k < 9; ++k) {
            const int oky = k / 3 - 1, okx = k % 3 - 1;
            int hh = h - oky, ww = w - okx;
            bool ok = (hh >= 0) & (hh < IMG) & (ww >= 0) & (ww < IMG);
            int hc = min(max(hh, 0), IMG - 1);
            int wcl = min(max(ww, 0), IMG - 1);
            const unsigned short* ap =
                Yatt + (size_t)(img * HW + hc * IMG + wcl) * YSTR + k * 10;
            ushort8 a8;
            __builtin_memcpy(&a8, ap, 16);   // 4-B aligned
            float a[9];
#pragma unroll
            for (int l = 0; l < 8; ++l) a[l] = bf2f(a8[l]);
            a[8] = bf2f(ap[8]);
            float m = -1e30f;
#pragma unroll
            for (int l = 0; l < 9; ++l) m = fmaxf(m, a[l]);
            float s = 0.f;
#pragma unroll
            for (int l = 0; l < 9; ++l) {
                a[l] = __expf((a[l] - m) * ATT_SCALE);
                s += a[l];
            }
            float g = ok ? (1.f / s) : 0.f;   // invalid neighbor contributes 0
#pragma unroll
            for (int l = 0; l < 9; ++l) {
                const int dy = (l / 3 - 1) - oky + 2;
                const int dx = (l % 3 - 1) - okx + 2;
                wc[dy * 5 + dx] += a[l] * g;
            }
        }
    }

    // ---- commit staged halo to LDS (plane-major: conflict-free writes) ----
#pragma unroll
    for (int i = 0; i < 6; ++i) {
        int u = i * 256 + t;
        int q = u / 384;
        int idx = u - q * 384;
        int vrow = idx >> 5, vcol = idx & 31;
        *(ushort8*)(vt + q * 6928 + (vrow * 36 + vcol) * 16) = stg[i];
    }
    __syncthreads();

    // ---- aggregate: 25 taps x 4 quarters, reads conflict-free, imm offsets --
    if (t < 224) {
        int base = (ph * 36 + pw) * 16;
        int pos = img * HW + h * IMG + w;
        unsigned short* fo = fold + (size_t)pos * NC + head * 32;
#pragma unroll
        for (int q = 0; q < 4; ++q) {
            const char* vq = vt + q * 6928 + base;
            float acc[8];
#pragma unroll
            for (int j = 0; j < 8; ++j) acc[j] = 0.f;
#pragma unroll
            for (int d = 0; d < 25; ++d) {
                const int dy = d / 5, dx = d % 5;
                float wf = wc[d];
                ushort8 vv = *(const ushort8*)(vq + (dy * 36 + dx) * 16);
#pragma unroll
                for (int j = 0; j < 8; ++j)
                    acc[j] += wf * bf2f(vv[j]);
            }
            ushort8 ov;
#pragma unroll
            for (int j = 0; j < 8; ++j) ov[j] = f2bf(acc[j]);
            *(ushort8*)(fo + q * 8) = ov;
        }
    }
}

extern "C" void kernel_launch(void* const* d_in, const int* in_sizes, int n_in,
                              void* d_out, int out_size, void* d_ws, size_t ws_size,
                              hipStream_t stream)
{
    const float* x  = (const float*)d_in[0];
    const float* Wv = (const float*)d_in[1];
    const float* Wa = (const float*)d_in[2];
    const float* ba = (const float*)d_in[3];
    const float* Wp = (const float*)d_in[4];
    const float* bp = (const float*)d_in[5];
    float* out = (float*)d_out;

    unsigned short* xt    = (unsigned short*)d_ws;       // 50176*192 (reused as fold)
    unsigned short* Y     = xt + 9633792;                // 50176*768
    unsigned short* Wall  = Y + 38535168;                // 768*192
    unsigned short* Wpt   = Wall + 147456;               // 192*192
    float*          ball  = (float*)(Wpt + 36864);       // 768 floats
    unsigned short* foldb = xt;                          // xt dead after gemm_big

    dim3 blk(256);
    prep_weights<<<576, blk, 0, stream>>>(Wv, Wa, Wp, ba, Wall, Wpt, ball);
    transpose_x<<<dim3(784, 3), blk, 0, stream>>>(x, xt);
    gemm_big<<<dim3(6, 392), blk, 0, stream>>>(xt, Wall, ball, Y);
    fused_att_agg<<<1344, blk, 0, stream>>>(Y, foldb);   // 16 img x 7 x 2 tiles x 6 heads
    gemm_small<<<dim3(196, 3), blk, 0, stream>>>(Wpt, foldb, bp, out);
}

// Round 3
// 192.282 us; speedup vs baseline: 1.0390x; 1.0390x over previous
//
#include <hip/hip_runtime.h>
#include <hip/hip_bf16.h>
#include <math.h>

#define HW 3136
#define NPOS 50176          // 16 images x 3136
#define NC 192
#define NHEADS 6
#define IMG 56
#define NATT 486
#define ATT_SCALE 0.17677669529663687f  // 32^-0.5

typedef __attribute__((ext_vector_type(8))) short short8;
typedef __attribute__((ext_vector_type(8))) unsigned short ushort8;
typedef __attribute__((ext_vector_type(4))) float float4v;
typedef __attribute__((ext_vector_type(4))) unsigned int uint4v;

__device__ __forceinline__ float bf2f(unsigned short u) {
    unsigned int x = ((unsigned int)u) << 16;
    return __builtin_bit_cast(float, x);
}
__device__ __forceinline__ float bf2f_lo(unsigned int u) {
    return __builtin_bit_cast(float, u << 16);
}
__device__ __forceinline__ float bf2f_hi(unsigned int u) {
    return __builtin_bit_cast(float, u & 0xffff0000u);
}
__device__ __forceinline__ unsigned short f2bf(float f) {
    __hip_bfloat16 h = __float2bfloat16(f);
    return __builtin_bit_cast(unsigned short, h);
}
__device__ __forceinline__ void gload_lds16(const void* g, void* l) {
    __builtin_amdgcn_global_load_lds((const __attribute__((address_space(1))) void*)g,
                                     (__attribute__((address_space(3))) void*)l, 16, 0, 0);
}

// x [16][192][3136] fp32 -> xt [50176][192] bf16 (channels-last). grid (784,3), block 256.
__global__ __launch_bounds__(256) void transpose_x(const float* __restrict__ x,
                                                   unsigned short* __restrict__ xt)
{
    __shared__ float tile[64][65];
    int bx = blockIdx.x;
    int n = (bx * 64) / HW;
    int hw0 = (bx * 64) % HW;
    int c0 = blockIdx.y * 64;
    int tl = threadIdx.x & 63, tg = threadIdx.x >> 6;
    const float* xn = x + (size_t)n * NC * HW;
#pragma unroll
    for (int i = 0; i < 16; ++i)
        tile[tg * 16 + i][tl] = xn[(size_t)(c0 + tg * 16 + i) * HW + hw0 + tl];
    __syncthreads();
    unsigned short* xp = xt + ((size_t)n * HW + hw0) * NC + c0;
#pragma unroll
    for (int i = 0; i < 16; ++i) {
        int hwr = tg * 16 + i;
        xp[(size_t)hwr * NC + tl] = f2bf(tile[tl][hwr]);
    }
}

// Weight prep: Wall[768][192] = [Wv^T ; Wa^T permuted, stride 10], ball[768],
// Wpt[192][192] = Wp^T. grid 576, block 256.
__global__ __launch_bounds__(256) void prep_weights(
    const float* __restrict__ Wv, const float* __restrict__ Wa, const float* __restrict__ Wp,
    const float* __restrict__ ba,
    unsigned short* __restrict__ Wall, unsigned short* __restrict__ Wpt,
    float* __restrict__ ball)
{
    int idx = blockIdx.x * 256 + threadIdx.x;
    if (idx < 36864) {
        int d = idx / 192, k = idx - d * 192;
        Wpt[idx] = f2bf(Wp[(size_t)k * NC + d]);
    }
    if (idx < 147456) {                       // 768*192
        int d = idx / 192, k = idx - d * 192;
        unsigned short val;
        float bv = 0.f;
        if (d < 192) {
            val = f2bf(Wv[(size_t)k * NC + d]);
        } else {
            int dp = d - 192;                 // 0..575
            int head = dp / 96, rr = dp - head * 96;
            int k9 = rr / 10, l = rr - k9 * 10;
            bool valid = (k9 < 9) && (l < 9);
            int src = head * 81 + k9 * 9 + l;
            val = valid ? f2bf(Wa[(size_t)k * NATT + src]) : (unsigned short)0;
            bv = valid ? ba[src] : 0.f;
        }
        Wall[idx] = val;
        if (k == 0) ball[d] = bv;
    }
}

// GEMM over all 768 output cols; epilogue scatters into fused-friendly layouts:
//   cols [0,192)   -> V[head][pos][32]           (64-B records)
//   cols [192,768) -> AT[head*9+k9][pos][10]     (20-B records; k9==9 pads dropped)
// 128x128 tile, 4 waves of 64x64 (4x4 acc), K=192 in 6 dbuf steps, glds16 staging.
// grid (6, 392).
__global__ __launch_bounds__(256) void gemm_big(
    const unsigned short* __restrict__ A, const unsigned short* __restrict__ W,
    const float* __restrict__ ball,
    unsigned short* __restrict__ Vo, unsigned short* __restrict__ ATo)
{
    __shared__ __align__(16) unsigned short As[2][4096];
    __shared__ __align__(16) unsigned short Bs[2][4096];
    int t = threadIdx.x, lane = t & 63, wave = t >> 6;
    int col0 = blockIdx.x * 128, row0 = blockIdx.y * 128;
    int fr = lane & 15, fq = lane >> 4;
    int wm = (wave >> 1) * 64, wn = (wave & 1) * 64;
    int srow = lane >> 2;          // 0..15
    int soff = (lane & 3) * 16;    // byte offset within a 64-B k-row chunk
    const char* Ab = (const char*)A;
    const char* Wb = (const char*)W;

    float4v acc[4][4] = {};

#define STAGE_BIG(buf, k0)                                                        \
    {                                                                             \
        _Pragma("unroll")                                                         \
        for (int i = 0; i < 2; ++i) {                                             \
            int j = wave * 2 + i;                                                 \
            gload_lds16(Ab + (size_t)(row0 + j * 16 + srow) * 384 + (k0)*2 + soff,\
                        (char*)As[buf] + j * 1024);                               \
            gload_lds16(Wb + (size_t)(col0 + j * 16 + srow) * 384 + (k0)*2 + soff,\
                        (char*)Bs[buf] + j * 1024);                               \
        }                                                                         \
    }

    STAGE_BIG(0, 0);
    for (int s = 0; s < 6; ++s) {
        if (s < 5) STAGE_BIG((s + 1) & 1, (s + 1) * 32);
        __syncthreads();
        int buf = s & 1;
        short8 af[4], bf[4];
#pragma unroll
        for (int mi = 0; mi < 4; ++mi)
            af[mi] = *(const short8*)((const char*)As[buf] + (wm + mi * 16 + fr) * 64 + fq * 16);
#pragma unroll
        for (int ni = 0; ni < 4; ++ni)
            bf[ni] = *(const short8*)((const char*)Bs[buf] + (wn + ni * 16 + fr) * 64 + fq * 16);
#pragma unroll
        for (int mi = 0; mi < 4; ++mi)
#pragma unroll
            for (int ni = 0; ni < 4; ++ni)
                acc[mi][ni] = __builtin_amdgcn_mfma_f32_16x16x32_bf16(
                    af[mi], bf[ni], acc[mi][ni], 0, 0, 0);
        __syncthreads();
    }

#pragma unroll
    for (int ni = 0; ni < 4; ++ni) {
        int col = col0 + wn + ni * 16 + fr;
        float b = ball[col];
        unsigned short* bptr;
        size_t rstr;
        bool valid;
        if (col < 192) {
            int hd = col >> 5, ch = col & 31;
            bptr = Vo + ((size_t)hd * NPOS) * 32 + ch;
            rstr = 32;
            valid = true;
        } else {
            int dp = col - 192;
            int hd = dp / 96, rr = dp - hd * 96;
            int k9 = rr / 10, l = rr - k9 * 10;
            valid = (k9 < 9);
            bptr = ATo + ((size_t)(hd * 9 + (k9 < 9 ? k9 : 8)) * NPOS) * 10 + l;
            rstr = 10;
        }
#pragma unroll
        for (int mi = 0; mi < 4; ++mi) {
            int row = row0 + wm + mi * 16 + fq * 4;
#pragma unroll
            for (int r = 0; r < 4; ++r) {
                unsigned short val = f2bf(acc[mi][ni][r] + b);
                if (valid) bptr[(size_t)(row + r) * rstr] = val;
            }
        }
    }
#undef STAGE_BIG
}

// out[img][m][phw] = sum_k Wpt[m][k]*fold[n][k] + bias[m]; 64(m) x 256(n) tile.
// grid (196, 3), block 256, 4 waves each 64x64.
__global__ __launch_bounds__(256) void gemm_small(
    const unsigned short* __restrict__ A,   // Wpt [192][192]
    const unsigned short* __restrict__ B,   // fold [50176][192]
    const float* __restrict__ bias, float* __restrict__ out)
{
    __shared__ __align__(16) unsigned short As[2][2048];
    __shared__ __align__(16) unsigned short Bs[2][8192];
    int t = threadIdx.x, lane = t & 63, wave = t >> 6;
    int n0 = blockIdx.x * 256, m0 = blockIdx.y * 64;
    int fr = lane & 15, fq = lane >> 4;
    int srow = lane >> 2, soff = (lane & 3) * 16;
    const char* Ab = (const char*)A;
    const char* Bb = (const char*)B;

    float4v acc[4][4] = {};

#define STAGE_SMALL(buf, k0)                                                      \
    {                                                                             \
        gload_lds16(Ab + (size_t)(m0 + wave * 16 + srow) * 384 + (k0)*2 + soff,   \
                    (char*)As[buf] + wave * 1024);                                \
        _Pragma("unroll")                                                         \
        for (int i = 0; i < 4; ++i) {                                             \
            int j = wave * 4 + i;                                                 \
            gload_lds16(Bb + (size_t)(n0 + j * 16 + srow) * 384 + (k0)*2 + soff,  \
                        (char*)Bs[buf] + j * 1024);                               \
        }                                                                         \
    }

    STAGE_SMALL(0, 0);
    for (int s = 0; s < 6; ++s) {
        if (s < 5) STAGE_SMALL((s + 1) & 1, (s + 1) * 32);
        __syncthreads();
        int buf = s & 1;
        short8 af[4], bf[4];
#pragma unroll
        for (int mi = 0; mi < 4; ++mi)
            af[mi] = *(const short8*)((const char*)As[buf] + (mi * 16 + fr) * 64 + fq * 16);
#pragma unroll
        for (int ni = 0; ni < 4; ++ni)
            bf[ni] = *(const short8*)((const char*)Bs[buf] + (wave * 64 + ni * 16 + fr) * 64 + fq * 16);
#pragma unroll
        for (int mi = 0; mi < 4; ++mi)
#pragma unroll
            for (int ni = 0; ni < 4; ++ni)
                acc[mi][ni] = __builtin_amdgcn_mfma_f32_16x16x32_bf16(
                    af[mi], bf[ni], acc[mi][ni], 0, 0, 0);
        __syncthreads();
    }

#pragma unroll
    for (int ni = 0; ni < 4; ++ni) {
        int n = n0 + wave * 64 + ni * 16 + fr;
        int img = n / HW, phw = n - img * HW;
        float* op = out + (size_t)img * (NC * HW) + phw;
#pragma unroll
        for (int mi = 0; mi < 4; ++mi) {
            int m = m0 + mi * 16 + fq * 4;
#pragma unroll
            for (int r = 0; r < 4; ++r)
                op[(size_t)(m + r) * HW] = acc[mi][ni][r] + bias[m + r];
        }
    }
#undef STAGE_SMALL
}

// Fused softmax + weight-combine + aggregation, v7: coalesced global layouts.
// Block = one head x (8x28) image tile (224 positions, 256 threads).
//  - V[head][pos][32]: halo staging reads are fully contiguous per wave.
//  - AT[head*9+k][pos][10]: softmax tap k reads consecutive pos across lanes.
//  - LDS: 4 q-planes, plane stride 434 chunks (16 B each; 434 mod 8 = 2 makes
//    the interleaved write mapping q=u&3 hit every bank-quad exactly 2x per
//    16-lane phase), row stride 36 chunks (read-balanced for the 28-wide map).
__global__ __launch_bounds__(256, 4) void fused_att_agg(
    const unsigned short* __restrict__ V, const unsigned short* __restrict__ AT,
    unsigned short* __restrict__ fold)
{
    __shared__ __align__(16) char vt[4 * 434 * 16];   // 27776 B
    int t = threadIdx.x;
    int bid = blockIdx.x;
    int head = bid % NHEADS; int tmp = bid / NHEADS;
    int tcol = tmp & 1; tmp >>= 1;
    int trow = tmp % 7; int img = tmp / 7;
    int h0 = trow * 8, w0 = tcol * 28;

    // ---- issue v-halo loads into registers (clamped addr + zero mask) ----
    const unsigned short* Vh = V + (size_t)head * NPOS * 32;
    ushort8 stg[6];
#pragma unroll
    for (int i = 0; i < 6; ++i) {
        int u = i * 256 + t;                 // 0..1535
        int slot = u >> 2, q = u & 3;        // slot = vrow*32+vcol, q = 16-B quarter
        int vrow = slot >> 5, vcol = slot & 31;
        int hh = h0 - 2 + vrow, ww = w0 - 2 + vcol;
        bool ok = (hh >= 0) & (hh < IMG) & (ww >= 0) & (ww < IMG);
        int hc = min(max(hh, 0), IMG - 1);
        int wcl = min(max(ww, 0), IMG - 1);
        ushort8 val = *(const ushort8*)(Vh + (size_t)(img * HW + hc * IMG + wcl) * 32 + q * 8);
        if (!ok) val = (ushort8){};
        stg[i] = val;
    }

    // ---- softmax -> 5x5 stencil weights, fully in registers ----
    int ph = t / 28, pw = t - (t / 28) * 28;
    int h = h0 + ph, w = w0 + pw;
    float wc[25];
#pragma unroll
    for (int d = 0; d < 25; ++d) wc[d] = 0.f;
    if (t < 224) {
        int head9 = head * 9;
#pragma unroll
        for (int k = 0; k < 9; ++k) {
            const int oky = k / 3 - 1, okx = k % 3 - 1;
            int hh = h - oky, ww = w - okx;
            bool ok = (hh >= 0) & (hh < IMG) & (ww >= 0) & (ww < IMG);
            int hc = min(max(hh, 0), IMG - 1);
            int wcl = min(max(ww, 0), IMG - 1);
            size_t nidx = (size_t)img * HW + hc * IMG + wcl;
            const unsigned int* ap32 =
                (const unsigned int*)(AT + ((size_t)(head9 + k) * NPOS + nidx) * 10);
            unsigned int u0 = ap32[0], u1 = ap32[1], u2 = ap32[2], u3 = ap32[3], u4 = ap32[4];
            float a[9] = { bf2f_lo(u0), bf2f_hi(u0), bf2f_lo(u1), bf2f_hi(u1),
                           bf2f_lo(u2), bf2f_hi(u2), bf2f_lo(u3), bf2f_hi(u3),
                           bf2f_lo(u4) };
            float m = -1e30f;
#pragma unroll
            for (int l = 0; l < 9; ++l) m = fmaxf(m, a[l]);
            float s = 0.f;
#pragma unroll
            for (int l = 0; l < 9; ++l) {
                a[l] = __expf((a[l] - m) * ATT_SCALE);
                s += a[l];
            }
            float g = ok ? (1.f / s) : 0.f;   // invalid neighbor contributes 0
#pragma unroll
            for (int l = 0; l < 9; ++l) {
                const int dy = (l / 3 - 1) - oky + 2;
                const int dx = (l % 3 - 1) - okx + 2;
                wc[dy * 5 + dx] += a[l] * g;
            }
        }
    }

    // ---- commit staged halo to LDS (write-balanced: plane stride 2 mod 8) ----
#pragma unroll
    for (int i = 0; i < 6; ++i) {
        int u = i * 256 + t;
        int slot = u >> 2, q = u & 3;
        int vrow = slot >> 5, vcol = slot & 31;
        *(ushort8*)(vt + q * (434 * 16) + (vrow * 36 + vcol) * 16) = stg[i];
    }
    __syncthreads();

    // ---- aggregate: 25 taps x 4 quarters, read-balanced, imm offsets ----
    if (t < 224) {
        int base = (ph * 36 + pw) * 16;
        int pos = img * HW + h * IMG + w;
        unsigned short* fo = fold + (size_t)pos * NC + head * 32;
#pragma unroll
        for (int q = 0; q < 4; ++q) {
            const char* vq = vt + q * (434 * 16) + base;
            float acc[8];
#pragma unroll
            for (int j = 0; j < 8; ++j) acc[j] = 0.f;
#pragma unroll
            for (int d = 0; d < 25; ++d) {
                const int dy = d / 5, dx = d % 5;
                float wf = wc[d];
                uint4v vv = *(const uint4v*)(vq + (dy * 36 + dx) * 16);
#pragma unroll
                for (int z = 0; z < 4; ++z) {
                    acc[2 * z]     += wf * bf2f_lo(vv[z]);
                    acc[2 * z + 1] += wf * bf2f_hi(vv[z]);
                }
            }
            ushort8 ov;
#pragma unroll
            for (int j = 0; j < 8; ++j) ov[j] = f2bf(acc[j]);
            *(ushort8*)(fo + q * 8) = ov;
        }
    }
}

extern "C" void kernel_launch(void* const* d_in, const int* in_sizes, int n_in,
                              void* d_out, int out_size, void* d_ws, size_t ws_size,
                              hipStream_t stream)
{
    const float* x  = (const float*)d_in[0];
    const float* Wv = (const float*)d_in[1];
    const float* Wa = (const float*)d_in[2];
    const float* ba = (const float*)d_in[3];
    const float* Wp = (const float*)d_in[4];
    const float* bp = (const float*)d_in[5];
    float* out = (float*)d_out;

    unsigned short* xt   = (unsigned short*)d_ws;        // 9,633,792 (reused as fold)
    unsigned short* V    = xt + 9633792;                 // 9,633,792
    unsigned short* AT   = V + 9633792;                  // 27,095,040
    unsigned short* Wall = AT + 27095040;                // 147,456
    unsigned short* Wpt  = Wall + 147456;                // 36,864
    float*          ball = (float*)(Wpt + 36864);        // 768 floats
    unsigned short* foldb = xt;                          // xt dead after gemm_big

    dim3 blk(256);
    prep_weights<<<576, blk, 0, stream>>>(Wv, Wa, Wp, ba, Wall, Wpt, ball);
    transpose_x<<<dim3(784, 3), blk, 0, stream>>>(x, xt);
    gemm_big<<<dim3(6, 392), blk, 0, stream>>>(xt, Wall, ball, V, AT);
    fused_att_agg<<<1344, blk, 0, stream>>>(V, AT, foldb);  // 16 img x 7 x 2 x 6 heads
    gemm_small<<<dim3(196, 3), blk, 0, stream>>>(Wpt, foldb, bp, out);
}

// Round 4
// 186.769 us; speedup vs baseline: 1.0696x; 1.0295x over previous
//
#include <hip/hip_runtime.h>
#include <hip/hip_bf16.h>
#include <math.h>

#define HW 3136
#define NPOS 50176          // 16 images x 3136
#define NC 192
#define NHEADS 6
#define IMG 56
#define NATT 486
#define ATT_SCALE 0.17677669529663687f  // 32^-0.5

typedef __attribute__((ext_vector_type(8))) short short8;
typedef __attribute__((ext_vector_type(8))) unsigned short ushort8;
typedef __attribute__((ext_vector_type(4))) float float4v;
typedef __attribute__((ext_vector_type(4))) unsigned int uint4v;

__device__ __forceinline__ float bf2f(unsigned short u) {
    unsigned int x = ((unsigned int)u) << 16;
    return __builtin_bit_cast(float, x);
}
__device__ __forceinline__ float bf2f_lo(unsigned int u) {
    return __builtin_bit_cast(float, u << 16);
}
__device__ __forceinline__ float bf2f_hi(unsigned int u) {
    return __builtin_bit_cast(float, u & 0xffff0000u);
}
__device__ __forceinline__ unsigned short f2bf(float f) {
    __hip_bfloat16 h = __float2bfloat16(f);
    return __builtin_bit_cast(unsigned short, h);
}
__device__ __forceinline__ void gload_lds16(const void* g, void* l) {
    __builtin_amdgcn_global_load_lds((const __attribute__((address_space(1))) void*)g,
                                     (__attribute__((address_space(3))) void*)l, 16, 0, 0);
}

// x [16][192][3136] fp32 -> xt [50176][192] bf16 (channels-last). grid (784,3), block 256.
__global__ __launch_bounds__(256) void transpose_x(const float* __restrict__ x,
                                                   unsigned short* __restrict__ xt)
{
    __shared__ float tile[64][65];
    int bx = blockIdx.x;
    int n = (bx * 64) / HW;
    int hw0 = (bx * 64) % HW;
    int c0 = blockIdx.y * 64;
    int tl = threadIdx.x & 63, tg = threadIdx.x >> 6;
    const float* xn = x + (size_t)n * NC * HW;
#pragma unroll
    for (int i = 0; i < 16; ++i)
        tile[tg * 16 + i][tl] = xn[(size_t)(c0 + tg * 16 + i) * HW + hw0 + tl];
    __syncthreads();
    unsigned short* xp = xt + ((size_t)n * HW + hw0) * NC + c0;
#pragma unroll
    for (int i = 0; i < 16; ++i) {
        int hwr = tg * 16 + i;
        xp[(size_t)hwr * NC + tl] = f2bf(tile[tl][hwr]);
    }
}

// Weight prep: Wall[768][192] = [Wv^T ; Wa^T permuted, stride 10], ball[768],
// Wpt[192][192] = Wp^T. grid 576, block 256.
__global__ __launch_bounds__(256) void prep_weights(
    const float* __restrict__ Wv, const float* __restrict__ Wa, const float* __restrict__ Wp,
    const float* __restrict__ ba,
    unsigned short* __restrict__ Wall, unsigned short* __restrict__ Wpt,
    float* __restrict__ ball)
{
    int idx = blockIdx.x * 256 + threadIdx.x;
    if (idx < 36864) {
        int d = idx / 192, k = idx - d * 192;
        Wpt[idx] = f2bf(Wp[(size_t)k * NC + d]);
    }
    if (idx < 147456) {                       // 768*192
        int d = idx / 192, k = idx - d * 192;
        unsigned short val;
        float bv = 0.f;
        if (d < 192) {
            val = f2bf(Wv[(size_t)k * NC + d]);
        } else {
            int dp = d - 192;                 // 0..575
            int head = dp / 96, rr = dp - head * 96;
            int k9 = rr / 10, l = rr - k9 * 10;
            bool valid = (k9 < 9) && (l < 9);
            int src = head * 81 + k9 * 9 + l;
            val = valid ? f2bf(Wa[(size_t)k * NATT + src]) : (unsigned short)0;
            bv = valid ? ba[src] : 0.f;
        }
        Wall[idx] = val;
        if (k == 0) ball[d] = bv;
    }
}

// GEMM over all 768 output cols; epilogue scatters into fused-friendly layouts:
//   cols [0,192)   -> V[head][pos][32]           (64-B records)
//   cols [192,768) -> AT[head*9+k9][pos][10]     (20-B records; k9==9 pads dropped)
// 128x128 tile, 4 waves of 64x64 (4x4 acc), K=192 in 6 steps.
// v8: counted-vmcnt 2-phase pipeline (prefetch stays in flight across barriers)
//     + XCD row-grouping swizzle: all 6 col-blocks of row-tile r on XCD r%8
//     (hw block i -> XCD i%8; 392 rows = 8*49 exactly). A-panel becomes L2-hit.
// grid 2352 (1-D), block 256.
__global__ __launch_bounds__(256) void gemm_big(
    const unsigned short* __restrict__ A, const unsigned short* __restrict__ W,
    const float* __restrict__ ball,
    unsigned short* __restrict__ Vo, unsigned short* __restrict__ ATo)
{
    __shared__ __align__(16) unsigned short As[2][4096];
    __shared__ __align__(16) unsigned short Bs[2][4096];
    int t = threadIdx.x, lane = t & 63, wave = t >> 6;
    int bi = blockIdx.x;
    int slot = bi >> 3;                // 0..293
    int q6 = slot / 6;
    int rr_ = (bi & 7) + 8 * q6;       // row-tile 0..391, xcd-grouped
    int cc_ = slot - 6 * q6;           // col-tile 0..5
    int col0 = cc_ * 128, row0 = rr_ * 128;
    int fr = lane & 15, fq = lane >> 4;
    int wm = (wave >> 1) * 64, wn = (wave & 1) * 64;
    int srow = lane >> 2;          // 0..15
    int soff = (lane & 3) * 16;    // byte offset within a 64-B k-row chunk
    const char* Ab = (const char*)A;
    const char* Wb = (const char*)W;

    float4v acc[4][4] = {};

#define STAGE_BIG(buf, k0)                                                        \
    {                                                                             \
        _Pragma("unroll")                                                         \
        for (int i = 0; i < 2; ++i) {                                             \
            int j = wave * 2 + i;                                                 \
            gload_lds16(Ab + (size_t)(row0 + j * 16 + srow) * 384 + (k0)*2 + soff,\
                        (char*)As[buf] + j * 1024);                               \
            gload_lds16(Wb + (size_t)(col0 + j * 16 + srow) * 384 + (k0)*2 + soff,\
                        (char*)Bs[buf] + j * 1024);                               \
        }                                                                         \
    }

    STAGE_BIG(0, 0);
    for (int s = 0; s < 6; ++s) {
        if (s < 5) {
            STAGE_BIG((s + 1) & 1, (s + 1) * 32);
            // wait only for current buffer's 4 loads; keep next 4 in flight
            asm volatile("s_waitcnt vmcnt(4)\n\ts_barrier" ::: "memory");
        } else {
            asm volatile("s_waitcnt vmcnt(0)\n\ts_barrier" ::: "memory");
        }
        int buf = s & 1;
        short8 af[4], bf[4];
#pragma unroll
        for (int mi = 0; mi < 4; ++mi)
            af[mi] = *(const short8*)((const char*)As[buf] + (wm + mi * 16 + fr) * 64 + fq * 16);
#pragma unroll
        for (int ni = 0; ni < 4; ++ni)
            bf[ni] = *(const short8*)((const char*)Bs[buf] + (wn + ni * 16 + fr) * 64 + fq * 16);
        // all LDS reads complete before any wave's next STAGE overwrites this buf
        asm volatile("s_waitcnt lgkmcnt(0)\n\ts_barrier" ::: "memory");
#pragma unroll
        for (int mi = 0; mi < 4; ++mi)
#pragma unroll
            for (int ni = 0; ni < 4; ++ni)
                acc[mi][ni] = __builtin_amdgcn_mfma_f32_16x16x32_bf16(
                    af[mi], bf[ni], acc[mi][ni], 0, 0, 0);
    }

#pragma unroll
    for (int ni = 0; ni < 4; ++ni) {
        int col = col0 + wn + ni * 16 + fr;
        float b = ball[col];
        unsigned short* bptr;
        size_t rstr;
        bool valid;
        if (col < 192) {
            int hd = col >> 5, ch = col & 31;
            bptr = Vo + ((size_t)hd * NPOS) * 32 + ch;
            rstr = 32;
            valid = true;
        } else {
            int dp = col - 192;
            int hd = dp / 96, rr = dp - hd * 96;
            int k9 = rr / 10, l = rr - k9 * 10;
            valid = (k9 < 9);
            bptr = ATo + ((size_t)(hd * 9 + (k9 < 9 ? k9 : 8)) * NPOS) * 10 + l;
            rstr = 10;
        }
#pragma unroll
        for (int mi = 0; mi < 4; ++mi) {
            int row = row0 + wm + mi * 16 + fq * 4;
#pragma unroll
            for (int r = 0; r < 4; ++r) {
                unsigned short val = f2bf(acc[mi][ni][r] + b);
                if (valid) bptr[(size_t)(row + r) * rstr] = val;
            }
        }
    }
#undef STAGE_BIG
}

// out[img][m][phw] = sum_k Wpt[m][k]*fold[n][k] + bias[m]; 64(m) x 256(n) tile.
// grid (196, 3), block 256, 4 waves each 64x64. v8: counted-vmcnt 2-phase.
__global__ __launch_bounds__(256) void gemm_small(
    const unsigned short* __restrict__ A,   // Wpt [192][192]
    const unsigned short* __restrict__ B,   // fold [50176][192]
    const float* __restrict__ bias, float* __restrict__ out)
{
    __shared__ __align__(16) unsigned short As[2][2048];
    __shared__ __align__(16) unsigned short Bs[2][8192];
    int t = threadIdx.x, lane = t & 63, wave = t >> 6;
    int n0 = blockIdx.x * 256, m0 = blockIdx.y * 64;
    int fr = lane & 15, fq = lane >> 4;
    int srow = lane >> 2, soff = (lane & 3) * 16;
    const char* Ab = (const char*)A;
    const char* Bb = (const char*)B;

    float4v acc[4][4] = {};

#define STAGE_SMALL(buf, k0)                                                      \
    {                                                                             \
        gload_lds16(Ab + (size_t)(m0 + wave * 16 + srow) * 384 + (k0)*2 + soff,   \
                    (char*)As[buf] + wave * 1024);                                \
        _Pragma("unroll")                                                         \
        for (int i = 0; i < 4; ++i) {                                             \
            int j = wave * 4 + i;                                                 \
            gload_lds16(Bb + (size_t)(n0 + j * 16 + srow) * 384 + (k0)*2 + soff,  \
                        (char*)Bs[buf] + j * 1024);                               \
        }                                                                         \
    }

    STAGE_SMALL(0, 0);
    for (int s = 0; s < 6; ++s) {
        if (s < 5) {
            STAGE_SMALL((s + 1) & 1, (s + 1) * 32);
            // wait only for current buffer's 5 loads; keep next 5 in flight
            asm volatile("s_waitcnt vmcnt(5)\n\ts_barrier" ::: "memory");
        } else {
            asm volatile("s_waitcnt vmcnt(0)\n\ts_barrier" ::: "memory");
        }
        int buf = s & 1;
        short8 af[4], bf[4];
#pragma unroll
        for (int mi = 0; mi < 4; ++mi)
            af[mi] = *(const short8*)((const char*)As[buf] + (mi * 16 + fr) * 64 + fq * 16);
#pragma unroll
        for (int ni = 0; ni < 4; ++ni)
            bf[ni] = *(const short8*)((const char*)Bs[buf] + (wave * 64 + ni * 16 + fr) * 64 + fq * 16);
        asm volatile("s_waitcnt lgkmcnt(0)\n\ts_barrier" ::: "memory");
#pragma unroll
        for (int mi = 0; mi < 4; ++mi)
#pragma unroll
            for (int ni = 0; ni < 4; ++ni)
                acc[mi][ni] = __builtin_amdgcn_mfma_f32_16x16x32_bf16(
                    af[mi], bf[ni], acc[mi][ni], 0, 0, 0);
    }

#pragma unroll
    for (int ni = 0; ni < 4; ++ni) {
        int n = n0 + wave * 64 + ni * 16 + fr;
        int img = n / HW, phw = n - img * HW;
        float* op = out + (size_t)img * (NC * HW) + phw;
#pragma unroll
        for (int mi = 0; mi < 4; ++mi) {
            int m = m0 + mi * 16 + fq * 4;
#pragma unroll
            for (int r = 0; r < 4; ++r)
                op[(size_t)(m + r) * HW] = acc[mi][ni][r] + bias[m + r];
        }
    }
#undef STAGE_SMALL
}

// Fused softmax + weight-combine + aggregation, v7: coalesced global layouts.
// Block = one head x (8x28) image tile (224 positions, 256 threads).
//  - V[head][pos][32]: halo staging reads are fully contiguous per wave.
//  - AT[head*9+k][pos][10]: softmax tap k reads consecutive pos across lanes.
//  - LDS: 4 q-planes, plane stride 434 chunks (16 B each; 434 mod 8 = 2 makes
//    the interleaved write mapping q=u&3 hit every bank-quad exactly 2x per
//    16-lane phase), row stride 36 chunks (read-balanced for the 28-wide map).
__global__ __launch_bounds__(256, 4) void fused_att_agg(
    const unsigned short* __restrict__ V, const unsigned short* __restrict__ AT,
    unsigned short* __restrict__ fold)
{
    __shared__ __align__(16) char vt[4 * 434 * 16];   // 27776 B
    int t = threadIdx.x;
    int bid = blockIdx.x;
    int head = bid % NHEADS; int tmp = bid / NHEADS;
    int tcol = tmp & 1; tmp >>= 1;
    int trow = tmp % 7; int img = tmp / 7;
    int h0 = trow * 8, w0 = tcol * 28;

    // ---- issue v-halo loads into registers (clamped addr + zero mask) ----
    const unsigned short* Vh = V + (size_t)head * NPOS * 32;
    ushort8 stg[6];
#pragma unroll
    for (int i = 0; i < 6; ++i) {
        int u = i * 256 + t;                 // 0..1535
        int slot = u >> 2, q = u & 3;        // slot = vrow*32+vcol, q = 16-B quarter
        int vrow = slot >> 5, vcol = slot & 31;
        int hh = h0 - 2 + vrow, ww = w0 - 2 + vcol;
        bool ok = (hh >= 0) & (hh < IMG) & (ww >= 0) & (ww < IMG);
        int hc = min(max(hh, 0), IMG - 1);
        int wcl = min(max(ww, 0), IMG - 1);
        ushort8 val = *(const ushort8*)(Vh + (size_t)(img * HW + hc * IMG + wcl) * 32 + q * 8);
        if (!ok) val = (ushort8){};
        stg[i] = val;
    }

    // ---- softmax -> 5x5 stencil weights, fully in registers ----
    int ph = t / 28, pw = t - (t / 28) * 28;
    int h = h0 + ph, w = w0 + pw;
    float wc[25];
#pragma unroll
    for (int d = 0; d < 25; ++d) wc[d] = 0.f;
    if (t < 224) {
        int head9 = head * 9;
#pragma unroll
        for (int k = 0; k < 9; ++k) {
            const int oky = k / 3 - 1, okx = k % 3 - 1;
            int hh = h - oky, ww = w - okx;
            bool ok = (hh >= 0) & (hh < IMG) & (ww >= 0) & (ww < IMG);
            int hc = min(max(hh, 0), IMG - 1);
            int wcl = min(max(ww, 0), IMG - 1);
            size_t nidx = (size_t)img * HW + hc * IMG + wcl;
            const unsigned int* ap32 =
                (const unsigned int*)(AT + ((size_t)(head9 + k) * NPOS + nidx) * 10);
            unsigned int u0 = ap32[0], u1 = ap32[1], u2 = ap32[2], u3 = ap32[3], u4 = ap32[4];
            float a[9] = { bf2f_lo(u0), bf2f_hi(u0), bf2f_lo(u1), bf2f_hi(u1),
                           bf2f_lo(u2), bf2f_hi(u2), bf2f_lo(u3), bf2f_hi(u3),
                           bf2f_lo(u4) };
            float m = -1e30f;
#pragma unroll
            for (int l = 0; l < 9; ++l) m = fmaxf(m, a[l]);
            float s = 0.f;
#pragma unroll
            for (int l = 0; l < 9; ++l) {
                a[l] = __expf((a[l] - m) * ATT_SCALE);
                s += a[l];
            }
            float g = ok ? (1.f / s) : 0.f;   // invalid neighbor contributes 0
#pragma unroll
            for (int l = 0; l < 9; ++l) {
                const int dy = (l / 3 - 1) - oky + 2;
                const int dx = (l % 3 - 1) - okx + 2;
                wc[dy * 5 + dx] += a[l] * g;
            }
        }
    }

    // ---- commit staged halo to LDS (write-balanced: plane stride 2 mod 8) ----
#pragma unroll
    for (int i = 0; i < 6; ++i) {
        int u = i * 256 + t;
        int slot = u >> 2, q = u & 3;
        int vrow = slot >> 5, vcol = slot & 31;
        *(ushort8*)(vt + q * (434 * 16) + (vrow * 36 + vcol) * 16) = stg[i];
    }
    __syncthreads();

    // ---- aggregate: 25 taps x 4 quarters, read-balanced, imm offsets ----
    if (t < 224) {
        int base = (ph * 36 + pw) * 16;
        int pos = img * HW + h * IMG + w;
        unsigned short* fo = fold + (size_t)pos * NC + head * 32;
#pragma unroll
        for (int q = 0; q < 4; ++q) {
            const char* vq = vt + q * (434 * 16) + base;
            float acc[8];
#pragma unroll
            for (int j = 0; j < 8; ++j) acc[j] = 0.f;
#pragma unroll
            for (int d = 0; d < 25; ++d) {
                const int dy = d / 5, dx = d % 5;
                float wf = wc[d];
                uint4v vv = *(const uint4v*)(vq + (dy * 36 + dx) * 16);
#pragma unroll
                for (int z = 0; z < 4; ++z) {
                    acc[2 * z]     += wf * bf2f_lo(vv[z]);
                    acc[2 * z + 1] += wf * bf2f_hi(vv[z]);
                }
            }
            ushort8 ov;
#pragma unroll
            for (int j = 0; j < 8; ++j) ov[j] = f2bf(acc[j]);
            *(ushort8*)(fo + q * 8) = ov;
        }
    }
}

extern "C" void kernel_launch(void* const* d_in, const int* in_sizes, int n_in,
                              void* d_out, int out_size, void* d_ws, size_t ws_size,
                              hipStream_t stream)
{
    const float* x  = (const float*)d_in[0];
    const float* Wv = (const float*)d_in[1];
    const float* Wa = (const float*)d_in[2];
    const float* ba = (const float*)d_in[3];
    const float* Wp = (const float*)d_in[4];
    const float* bp = (const float*)d_in[5];
    float* out = (float*)d_out;

    unsigned short* xt   = (unsigned short*)d_ws;        // 9,633,792 (reused as fold)
    unsigned short* V    = xt + 9633792;                 // 9,633,792
    unsigned short* AT   = V + 9633792;                  // 27,095,040
    unsigned short* Wall = AT + 27095040;                // 147,456
    unsigned short* Wpt  = Wall + 147456;                // 36,864
    float*          ball = (float*)(Wpt + 36864);        // 768 floats
    unsigned short* foldb = xt;                          // xt dead after gemm_big

    dim3 blk(256);
    prep_weights<<<576, blk, 0, stream>>>(Wv, Wa, Wp, ba, Wall, Wpt, ball);
    transpose_x<<<dim3(784, 3), blk, 0, stream>>>(x, xt);
    gemm_big<<<2352, blk, 0, stream>>>(xt, Wall, ball, V, AT);
    fused_att_agg<<<1344, blk, 0, stream>>>(V, AT, foldb);  // 16 img x 7 x 2 x 6 heads
    gemm_small<<<dim3(196, 3), blk, 0, stream>>>(Wpt, foldb, bp, out);
}